// Round 7
// baseline (930.879 us; speedup 1.0000x reference)
//
#include <hip/hip_runtime.h>
#include <hip/hip_bf16.h>
#include <math.h>

typedef __attribute__((ext_vector_type(8))) short short8;
typedef __attribute__((ext_vector_type(4))) float f32x4;
typedef __attribute__((ext_vector_type(4))) int i32x4;
typedef unsigned short u16;
typedef unsigned int u32;
typedef unsigned long long u64;

__device__ __forceinline__ u16 f2bf(float f) {
  union { float f; u32 u; } x; x.f = f;
  return (u16)((x.u + 0x7fffu + ((x.u >> 16) & 1u)) >> 16);
}
__device__ __forceinline__ float bf2f(u32 bits) {
  union { u32 u; float f; } x; x.u = bits; return x.f;
}
__device__ __forceinline__ float sigm(float v) { return 1.0f / (1.0f + __expf(-v)); }

#define MFMA __builtin_amdgcn_mfma_f32_16x16x32_bf16
#define HS 262144  // 512*512 u16 per ring slot

// 16 x 16B loads (stride 64B) in one asm block, single latency exposure.
#define LDG16_BODY(FL)                                        \
    "global_load_dwordx4 %0, %16, off " FL "\n\t"             \
    "global_load_dwordx4 %1, %16, off offset:64 " FL "\n\t"   \
    "global_load_dwordx4 %2, %16, off offset:128 " FL "\n\t"  \
    "global_load_dwordx4 %3, %16, off offset:192 " FL "\n\t"  \
    "global_load_dwordx4 %4, %16, off offset:256 " FL "\n\t"  \
    "global_load_dwordx4 %5, %16, off offset:320 " FL "\n\t"  \
    "global_load_dwordx4 %6, %16, off offset:384 " FL "\n\t"  \
    "global_load_dwordx4 %7, %16, off offset:448 " FL "\n\t"  \
    "global_load_dwordx4 %8, %16, off offset:512 " FL "\n\t"  \
    "global_load_dwordx4 %9, %16, off offset:576 " FL "\n\t"  \
    "global_load_dwordx4 %10, %16, off offset:640 " FL "\n\t" \
    "global_load_dwordx4 %11, %16, off offset:704 " FL "\n\t" \
    "global_load_dwordx4 %12, %16, off offset:768 " FL "\n\t" \
    "global_load_dwordx4 %13, %16, off offset:832 " FL "\n\t" \
    "global_load_dwordx4 %14, %16, off offset:896 " FL "\n\t" \
    "global_load_dwordx4 %15, %16, off offset:960 " FL "\n\t" \
    "s_waitcnt vmcnt(0)"
#define LDG16_OPS(a, base)                                                     \
    : "=&v"(a[0]), "=&v"(a[1]), "=&v"(a[2]), "=&v"(a[3]), "=&v"(a[4]),         \
      "=&v"(a[5]), "=&v"(a[6]), "=&v"(a[7]), "=&v"(a[8]), "=&v"(a[9]),         \
      "=&v"(a[10]), "=&v"(a[11]), "=&v"(a[12]), "=&v"(a[13]), "=&v"(a[14]),    \
      "=&v"(a[15])                                                             \
    : "v"(base) : "memory"

__device__ __forceinline__ void ldg16_sc0(short8 a[16], const u16* base) {
  asm volatile(LDG16_BODY("sc0") LDG16_OPS(a, base));
}
__device__ __forceinline__ void ldg16_sc01(short8 a[16], const u16* base) {
  asm volatile(LDG16_BODY("sc0 sc1") LDG16_OPS(a, base));
}
__device__ __forceinline__ void stg4_sc01(void* p, i32x4 v) {
  asm volatile("global_store_dwordx4 %0, %1, off sc0 sc1" :: "v"(p), "v"(v) : "memory");
}
__device__ __forceinline__ void stg1_sc01(void* p, u32 v) {
  asm volatile("global_store_dword %0, %1, off sc0 sc1" :: "v"(p), "v"(v) : "memory");
}

// All-thread poll of a packed (c0,c1) counter pair; no barrier needed after.
__device__ __forceinline__ void waitpair(const u64* p, u32 tlo, u32 thi) {
  while (true) {
    u64 v = __hip_atomic_load(p, __ATOMIC_RELAXED, __HIP_MEMORY_SCOPE_AGENT);
    if ((u32)v >= tlo && (u32)(v >> 32) >= thi) return;
    __builtin_amdgcn_s_sleep(1);
  }
}

// Persistent fused 2-layer GRU, decoupled pipeline, zero steady-state fences,
// COALESCED publish (in-wave LDS transpose -> dwordx4 stores), y via private
// slab + final reduction (no atomics on the recurrence).
__global__ __launch_bounds__(256, 1) void gru_fused(
    const float* __restrict__ xin, const float* __restrict__ h1in, const float* __restrict__ h2in,
    const float* __restrict__ Wih1, const float* __restrict__ Whh1,
    const float* __restrict__ bih1, const float* __restrict__ bhh1,
    const float* __restrict__ Wih2, const float* __restrict__ Whh2,
    const float* __restrict__ bih2, const float* __restrict__ bhh2,
    const float* __restrict__ Wfc, const float* __restrict__ bfc,
    float* __restrict__ out, u16* __restrict__ wsb, unsigned* __restrict__ barc)
{
  const int bid   = blockIdx.x;
  const int rb    = bid & 3;
  const int layer = (bid >> 2) & 1;
  const int cbl   = bid >> 3;
  const int n0    = cbl * 16;
  const int wid   = bid >> 2;
  const int tid   = threadIdx.x;
  const int w     = tid >> 6;
  const int lane  = tid & 63;
  const int quad  = lane >> 4;
  const int m16   = lane & 15;

  u16* x0  = wsb;                     // [512][576] bf16 (immutable after init)
  u16* x1  = x0 + 512 * 576;          // shifted copy
  u16* h1r = x1 + 512 * 576;          // 4-slot ring, layer-0 local
  u16* h2r = h1r + 4 * HS;            // 4-slot ring, layer-1 local
  u16* h1m = h2r + 4 * HS;            // 4-slot MALL mirror of h1
  u32* ysl = (u32*)(h1m + 4 * HS);    // y slab [32 cb][512 row][64 t] fp32

  __shared__ short8 wlds[96 * 64];    // 96 KB weight fragments
  __shared__ u32 stage[4 * 288];      // per-wave transpose stage (9-dw pad)

  u64* pair = (u64*)(barc + rb * 16); // lo=c0 (layer0 arrivals), hi=c1
  u32* c0   = (u32*)pair;
  u32* c1   = c0 + 1;
  u32* cinit = barc + 128;
  u32* cfin  = barc + 132;

  const float* Wih = layer ? Wih2 : Wih1;
  const float* Whh = layer ? Whh2 : Whh1;
  const float* bih = layer ? bih2 : bih1;
  const float* bhh = layer ? bhh2 : bhh1;

  // ---------------- one-time init ----------------
  for (int i = wid * 256 + tid; i < 128 * 575; i += 64 * 256) {
    int r = i / 575, c = i - r * 575;
    int row = rb * 128 + r;
    u16 bv = f2bf(xin[row * 575 + c]);
    x0[row * 576 + c] = bv;
    if (c >= 1) x1[row * 576 + (c - 1)] = bv;
  }
  for (int i = wid * 256 + tid; i < 128 * 512; i += 64 * 256) {
    int r = i >> 9, c = i & 511;
    int row = rb * 128 + r;
    h1r[3 * HS + row * 512 + c] = f2bf(h1in[row * 512 + c]);
    h2r[3 * HS + row * 512 + c] = f2bf(h2in[row * 512 + c]);
  }
  for (int i = tid; i < 96 * 64; i += 256) {
    int blk = i >> 6, l = i & 63;
    int s, gr;
    if (blk < 64) { s = blk & 31; gr = (blk >> 5) * 512; }   // r / z, K=1024
    else          { s = blk - 64; gr = 1024; }               // i_n (s<16) / h_n (s>=16)
    int n  = n0 + (l & 15);
    int k0 = s * 32 + (l >> 4) * 8;
    short8 pk;
    #pragma unroll
    for (int j = 0; j < 8; ++j) {
      int k = k0 + j;
      float v = (k < 512) ? Wih[(gr + n) * 512 + k] : Whh[(gr + n) * 512 + (k - 512)];
      pk[j] = (short)f2bf(v);
    }
    wlds[blk * 64 + l] = pk;
  }

  float hreg[2][4];
  const float* hin = layer ? h2in : h1in;
  #pragma unroll
  for (int rf = 0; rf < 2; ++rf)
    #pragma unroll
    for (int q = 0; q < 4; ++q)
      hreg[rf][q] = hin[(rb * 128 + (2 * w + rf) * 16 + quad * 4 + q) * 512 + n0 + m16];

  const int nn = n0 + m16;
  const float bias_r  = bih[nn] + bhh[nn];
  const float bias_z  = bih[512 + nn] + bhh[512 + nn];
  const float bias_in = bih[1024 + nn];
  const float bias_hn = bhh[1024 + nn];
  const float bfcv = bfc[0];
  float wfc8[8];
  #pragma unroll
  for (int k = 0; k < 8; ++k) wfc8[k] = Wfc[n0 + (lane & 1) * 8 + k];

  // one-time init barrier with release/acquire (flush init data + drop poison)
  __syncthreads();
  if (tid == 0) {
    __builtin_amdgcn_fence(__ATOMIC_RELEASE, "agent");
    __hip_atomic_fetch_add(cinit, 1u, __ATOMIC_RELAXED, __HIP_MEMORY_SCOPE_AGENT);
    while (__hip_atomic_load(cinit, __ATOMIC_RELAXED, __HIP_MEMORY_SCOPE_AGENT) < 256u)
      __builtin_amdgcn_s_sleep(1);
    __builtin_amdgcn_fence(__ATOMIC_ACQUIRE, "agent");
  }
  __syncthreads();

  const int arow0 = rb * 128 + (2 * w) * 16 + m16;
  const int arow1 = arow0 + 16;
  const int rl    = lane >> 1;        // transpose-read row (wave-local 0..31)
  const int hl    = lane & 1;         // column half (8 cols)
  const int growt = rb * 128 + w * 32 + rl;

  if (layer == 0) {
    // =================== producer: h1(u) ===================
    for (int u = 0; u < 64; ++u) {
      f32x4 acc[2][4] = {};
      // x-half before the wait (overlaps peers' completion)
      {
        const int c = u & 1;
        const u16* xc = c ? x1 : x0;
        const u32* pa0 = (const u32*)(xc + (size_t)arow0 * 576 + (u - c) + quad * 8);
        const u32* pa1 = (const u32*)(xc + (size_t)arow1 * 576 + (u - c) + quad * 8);
        #pragma unroll
        for (int s = 0; s < 16; ++s) {
          union { short8 v; u32 u4[4]; } a0, a1;
          #pragma unroll
          for (int j = 0; j < 4; ++j) { a0.u4[j] = pa0[s * 16 + j]; a1.u4[j] = pa1[s * 16 + j]; }
          short8 br = wlds[(s)      * 64 + lane];
          short8 bz = wlds[(32 + s) * 64 + lane];
          short8 bi = wlds[(64 + s) * 64 + lane];
          acc[0][0] = MFMA(a0.v, br, acc[0][0], 0, 0, 0);
          acc[1][0] = MFMA(a1.v, br, acc[1][0], 0, 0, 0);
          acc[0][1] = MFMA(a0.v, bz, acc[0][1], 0, 0, 0);
          acc[1][1] = MFMA(a1.v, bz, acc[1][1], 0, 0, 0);
          acc[0][2] = MFMA(a0.v, bi, acc[0][2], 0, 0, 0);
          acc[1][2] = MFMA(a1.v, bi, acc[1][2], 0, 0, 0);
        }
      }
      // wait: peers wrote h1(u-1); h1m slot u&3 free (consumers past u-4)
      waitpair(pair, 32u * (unsigned)u, u >= 4 ? 32u * (unsigned)(u - 3) : 0u);
      // h-half: sc0 loads from local-L2 ring
      #pragma unroll
      for (int rf = 0; rf < 2; ++rf) {
        short8 a[16];
        const u16* base = h1r + (size_t)((u + 3) & 3) * HS +
                          (size_t)(rf ? arow1 : arow0) * 512 + quad * 8;
        ldg16_sc0(a, base);
        #pragma unroll
        for (int s = 0; s < 16; ++s) {
          short8 br = wlds[(16 + s) * 64 + lane];
          short8 bz = wlds[(48 + s) * 64 + lane];
          short8 bh = wlds[(80 + s) * 64 + lane];
          acc[rf][0] = MFMA(a[s], br, acc[rf][0], 0, 0, 0);
          acc[rf][1] = MFMA(a[s], bz, acc[rf][1], 0, 0, 0);
          acc[rf][3] = MFMA(a[s], bh, acc[rf][3], 0, 0, 0);
        }
      }
      // gates -> stage (in-wave transpose to row-major)
      #pragma unroll
      for (int rf = 0; rf < 2; ++rf)
        #pragma unroll
        for (int q = 0; q < 4; ++q) {
          float rg = sigm(acc[rf][0][q] + bias_r);
          float zg = sigm(acc[rf][1][q] + bias_z);
          float ng = tanhf(acc[rf][2][q] + bias_in + rg * (acc[rf][3][q] + bias_hn));
          float hv = (1.0f - zg) * ng + zg * hreg[rf][q];
          hreg[rf][q] = hv;
          u16 b = f2bf(hv);
          u32 pv = (u32)b | ((u32)(u16)__shfl_xor((int)b, 1) << 16);
          if (!(m16 & 1))
            stage[w * 288 + (rf * 16 + quad * 4 + q) * 9 + (m16 >> 1)] = pv;
        }
      // gather 16B row-run and publish (local plain + mirror sc0sc1)
      {
        i32x4 dv;
        dv.x = (int)stage[w * 288 + rl * 9 + hl * 4 + 0];
        dv.y = (int)stage[w * 288 + rl * 9 + hl * 4 + 1];
        dv.z = (int)stage[w * 288 + rl * 9 + hl * 4 + 2];
        dv.w = (int)stage[w * 288 + rl * 9 + hl * 4 + 3];
        size_t off = (size_t)(u & 3) * HS + (size_t)growt * 512 + n0 + hl * 8;
        *(i32x4*)(h1r + off) = dv;
        stg4_sc01(h1m + off, dv);
      }
      asm volatile("s_waitcnt vmcnt(0)" ::: "memory");
      __syncthreads();
      if (tid == 0)
        __hip_atomic_fetch_add(c0, 1u, __ATOMIC_RELAXED, __HIP_MEMORY_SCOPE_AGENT);
    }
  } else {
    // =================== consumer: h2(v) + y(v) ===================
    for (int v = 0; v < 64; ++v) {
      f32x4 acc[2][4] = {};
      waitpair(pair, 32u * (unsigned)(v + 1), 32u * (unsigned)v);
      // h2-half: local L2 (sc0)
      #pragma unroll
      for (int rf = 0; rf < 2; ++rf) {
        short8 a[16];
        const u16* base = h2r + (size_t)((v + 3) & 3) * HS +
                          (size_t)(rf ? arow1 : arow0) * 512 + quad * 8;
        ldg16_sc0(a, base);
        #pragma unroll
        for (int s = 0; s < 16; ++s) {
          short8 br = wlds[(16 + s) * 64 + lane];
          short8 bz = wlds[(48 + s) * 64 + lane];
          short8 bh = wlds[(80 + s) * 64 + lane];
          acc[rf][0] = MFMA(a[s], br, acc[rf][0], 0, 0, 0);
          acc[rf][1] = MFMA(a[s], bz, acc[rf][1], 0, 0, 0);
          acc[rf][3] = MFMA(a[s], bh, acc[rf][3], 0, 0, 0);
        }
      }
      // h1-half: MALL mirror (sc0 sc1)
      #pragma unroll
      for (int rf = 0; rf < 2; ++rf) {
        short8 a[16];
        const u16* base = h1m + (size_t)(v & 3) * HS +
                          (size_t)(rf ? arow1 : arow0) * 512 + quad * 8;
        ldg16_sc01(a, base);
        #pragma unroll
        for (int s = 0; s < 16; ++s) {
          short8 br = wlds[(s)      * 64 + lane];
          short8 bz = wlds[(32 + s) * 64 + lane];
          short8 bi = wlds[(64 + s) * 64 + lane];
          acc[rf][0] = MFMA(a[s], br, acc[rf][0], 0, 0, 0);
          acc[rf][1] = MFMA(a[s], bz, acc[rf][1], 0, 0, 0);
          acc[rf][2] = MFMA(a[s], bi, acc[rf][2], 0, 0, 0);
        }
      }
      // gates -> stage
      #pragma unroll
      for (int rf = 0; rf < 2; ++rf)
        #pragma unroll
        for (int q = 0; q < 4; ++q) {
          float rg = sigm(acc[rf][0][q] + bias_r);
          float zg = sigm(acc[rf][1][q] + bias_z);
          float ng = tanhf(acc[rf][2][q] + bias_in + rg * (acc[rf][3][q] + bias_hn));
          float hv = (1.0f - zg) * ng + zg * hreg[rf][q];
          hreg[rf][q] = hv;
          u16 b = f2bf(hv);
          u32 pv = (u32)b | ((u32)(u16)__shfl_xor((int)b, 1) << 16);
          if (!(m16 & 1))
            stage[w * 288 + (rf * 16 + quad * 4 + q) * 9 + (m16 >> 1)] = pv;
        }
      // gather + publish h2 (local) + y partial to slab (sc0sc1)
      {
        i32x4 dv;
        dv.x = (int)stage[w * 288 + rl * 9 + hl * 4 + 0];
        dv.y = (int)stage[w * 288 + rl * 9 + hl * 4 + 1];
        dv.z = (int)stage[w * 288 + rl * 9 + hl * 4 + 2];
        dv.w = (int)stage[w * 288 + rl * 9 + hl * 4 + 3];
        size_t off = (size_t)(v & 3) * HS + (size_t)growt * 512 + n0 + hl * 8;
        *(i32x4*)(h2r + off) = dv;
        float yl = 0.0f;
        u32 dd[4] = {(u32)dv.x, (u32)dv.y, (u32)dv.z, (u32)dv.w};
        #pragma unroll
        for (int j = 0; j < 4; ++j) {
          yl += bf2f(dd[j] << 16) * wfc8[2 * j];
          yl += bf2f(dd[j] & 0xffff0000u) * wfc8[2 * j + 1];
        }
        yl += __shfl_xor(yl, 1);
        if (!hl) {
          union { float f; u32 u; } yu; yu.f = yl;
          stg1_sc01(ysl + ((size_t)(cbl * 512 + growt) * 64 + v), yu.u);
        }
      }
      asm volatile("s_waitcnt vmcnt(0)" ::: "memory");
      __syncthreads();
      if (tid == 0)
        __hip_atomic_fetch_add(c1, 1u, __ATOMIC_RELAXED, __HIP_MEMORY_SCOPE_AGENT);
    }
  }

  // final hidden states from registers (fp32 exact)
  float* hout = out + 32768 + layer * (512 * 512);
  #pragma unroll
  for (int rf = 0; rf < 2; ++rf)
    #pragma unroll
    for (int q = 0; q < 4; ++q) {
      int row = rb * 128 + (2 * w + rf) * 16 + quad * 4 + q;
      hout[row * 512 + nn] = hreg[rf][q];
    }

  // grid-wide completion barrier, then y reduction (32 partials per output)
  asm volatile("s_waitcnt vmcnt(0)" ::: "memory");
  __syncthreads();
  if (tid == 0)
    __hip_atomic_fetch_add(cfin, 1u, __ATOMIC_RELAXED, __HIP_MEMORY_SCOPE_AGENT);
  while (__hip_atomic_load(cfin, __ATOMIC_RELAXED, __HIP_MEMORY_SCOPE_AGENT) < 256u)
    __builtin_amdgcn_s_sleep(1);

  if (tid < 128) {
    int row = 2 * bid + (tid >> 6);
    int t   = tid & 63;
    float acc = bfcv;
    #pragma unroll
    for (int cb = 0; cb < 32; ++cb) {
      u32 bits = __hip_atomic_load(ysl + ((size_t)(cb * 512 + row) * 64 + t),
                                   __ATOMIC_RELAXED, __HIP_MEMORY_SCOPE_AGENT);
      union { u32 u; float f; } cv; cv.u = bits;
      acc += cv.f;
    }
    out[row * 64 + t] = acc;
  }
}

extern "C" void kernel_launch(void* const* d_in, const int* in_sizes, int n_in,
                              void* d_out, int out_size, void* d_ws, size_t ws_size,
                              hipStream_t stream) {
  (void)in_sizes; (void)n_in; (void)out_size; (void)ws_size;
  (void)hipMemsetAsync(d_ws, 0, 4096, stream);               // arrival counters
  unsigned* bar = (unsigned*)d_ws;
  u16* wsb = (u16*)((char*)d_ws + 4096);
  gru_fused<<<256, 256, 0, stream>>>(
      (const float*)d_in[0], (const float*)d_in[1], (const float*)d_in[2],
      (const float*)d_in[3], (const float*)d_in[4], (const float*)d_in[5], (const float*)d_in[6],
      (const float*)d_in[7], (const float*)d_in[8], (const float*)d_in[9], (const float*)d_in[10],
      (const float*)d_in[11], (const float*)d_in[12],
      (float*)d_out, wsb, bar);
}

// Round 9
// 848.101 us; speedup vs baseline: 1.0976x; 1.0976x over previous
//
#include <hip/hip_runtime.h>
#include <hip/hip_bf16.h>
#include <math.h>

typedef __attribute__((ext_vector_type(8))) short short8;
typedef __attribute__((ext_vector_type(4))) float f32x4;
typedef __attribute__((ext_vector_type(4))) int i32x4;
typedef unsigned short u16;
typedef unsigned int u32;
typedef unsigned long long u64;

__device__ __forceinline__ u16 f2bf(float f) {
  union { float f; u32 u; } x; x.f = f;
  return (u16)((x.u + 0x7fffu + ((x.u >> 16) & 1u)) >> 16);
}
__device__ __forceinline__ float bf2f(u32 bits) {
  union { u32 u; float f; } x; x.u = bits; return x.f;
}
__device__ __forceinline__ float sigm(float v) { return 1.0f / (1.0f + __expf(-v)); }

#define MFMA __builtin_amdgcn_mfma_f32_16x16x32_bf16
#define HS 262144  // 512*512 u16 per ring slot

// 32 x 16B loads (two 16-row fragments) in ONE asm block, single vmcnt(0).
#define LDG32_BODY(FL)                                         \
    "global_load_dwordx4 %0, %32, off " FL "\n\t"              \
    "global_load_dwordx4 %1, %32, off offset:64 " FL "\n\t"    \
    "global_load_dwordx4 %2, %32, off offset:128 " FL "\n\t"   \
    "global_load_dwordx4 %3, %32, off offset:192 " FL "\n\t"   \
    "global_load_dwordx4 %4, %32, off offset:256 " FL "\n\t"   \
    "global_load_dwordx4 %5, %32, off offset:320 " FL "\n\t"   \
    "global_load_dwordx4 %6, %32, off offset:384 " FL "\n\t"   \
    "global_load_dwordx4 %7, %32, off offset:448 " FL "\n\t"   \
    "global_load_dwordx4 %8, %32, off offset:512 " FL "\n\t"   \
    "global_load_dwordx4 %9, %32, off offset:576 " FL "\n\t"   \
    "global_load_dwordx4 %10, %32, off offset:640 " FL "\n\t"  \
    "global_load_dwordx4 %11, %32, off offset:704 " FL "\n\t"  \
    "global_load_dwordx4 %12, %32, off offset:768 " FL "\n\t"  \
    "global_load_dwordx4 %13, %32, off offset:832 " FL "\n\t"  \
    "global_load_dwordx4 %14, %32, off offset:896 " FL "\n\t"  \
    "global_load_dwordx4 %15, %32, off offset:960 " FL "\n\t"  \
    "global_load_dwordx4 %16, %33, off " FL "\n\t"             \
    "global_load_dwordx4 %17, %33, off offset:64 " FL "\n\t"   \
    "global_load_dwordx4 %18, %33, off offset:128 " FL "\n\t"  \
    "global_load_dwordx4 %19, %33, off offset:192 " FL "\n\t"  \
    "global_load_dwordx4 %20, %33, off offset:256 " FL "\n\t"  \
    "global_load_dwordx4 %21, %33, off offset:320 " FL "\n\t"  \
    "global_load_dwordx4 %22, %33, off offset:384 " FL "\n\t"  \
    "global_load_dwordx4 %23, %33, off offset:448 " FL "\n\t"  \
    "global_load_dwordx4 %24, %33, off offset:512 " FL "\n\t"  \
    "global_load_dwordx4 %25, %33, off offset:576 " FL "\n\t"  \
    "global_load_dwordx4 %26, %33, off offset:640 " FL "\n\t"  \
    "global_load_dwordx4 %27, %33, off offset:704 " FL "\n\t"  \
    "global_load_dwordx4 %28, %33, off offset:768 " FL "\n\t"  \
    "global_load_dwordx4 %29, %33, off offset:832 " FL "\n\t"  \
    "global_load_dwordx4 %30, %33, off offset:896 " FL "\n\t"  \
    "global_load_dwordx4 %31, %33, off offset:960 " FL "\n\t"  \
    "s_waitcnt vmcnt(0)"
#define LDG32_OPS(a, b0, b1)                                                   \
    : "=&v"(a[0]), "=&v"(a[1]), "=&v"(a[2]), "=&v"(a[3]), "=&v"(a[4]),         \
      "=&v"(a[5]), "=&v"(a[6]), "=&v"(a[7]), "=&v"(a[8]), "=&v"(a[9]),         \
      "=&v"(a[10]), "=&v"(a[11]), "=&v"(a[12]), "=&v"(a[13]), "=&v"(a[14]),    \
      "=&v"(a[15]), "=&v"(a[16]), "=&v"(a[17]), "=&v"(a[18]), "=&v"(a[19]),    \
      "=&v"(a[20]), "=&v"(a[21]), "=&v"(a[22]), "=&v"(a[23]), "=&v"(a[24]),    \
      "=&v"(a[25]), "=&v"(a[26]), "=&v"(a[27]), "=&v"(a[28]), "=&v"(a[29]),    \
      "=&v"(a[30]), "=&v"(a[31])                                               \
    : "v"(b0), "v"(b1) : "memory"

__device__ __forceinline__ void ldg32_sc0(short8 a[32], const u16* b0, const u16* b1) {
  asm volatile(LDG32_BODY("sc0") LDG32_OPS(a, b0, b1));
}
__device__ __forceinline__ void ldg32_sc01(short8 a[32], const u16* b0, const u16* b1) {
  asm volatile(LDG32_BODY("sc0 sc1") LDG32_OPS(a, b0, b1));
}
__device__ __forceinline__ void stg4_sc01(void* p, i32x4 v) {
  asm volatile("global_store_dwordx4 %0, %1, off sc0 sc1" :: "v"(p), "v"(v) : "memory");
}
__device__ __forceinline__ void stg1_sc01(void* p, u32 v) {
  asm volatile("global_store_dword %0, %1, off sc0 sc1" :: "v"(p), "v"(v) : "memory");
}
// Per-WG flag release: plain dword store straight to MALL (sc0 sc1), no RMW.
__device__ __forceinline__ void stflag(u32* p, u32 v) {
  asm volatile("global_store_dword %0, %1, off sc0 sc1\n\ts_waitcnt vmcnt(0)"
               :: "v"(p), "v"(v) : "memory");
}
__device__ __forceinline__ u32 ldflag(const u32* p) {
  u32 v;
  asm volatile("global_load_dword %0, %1, off sc0 sc1\n\ts_waitcnt vmcnt(0)"
               : "=v"(v) : "v"(p) : "memory");
  return v;
}

// Vectorized flag wait: lane i polls flags[i]; lanes<32 = layer-0 WG flags
// (target t0), lanes>=32 = layer-1 flags (target t1). One MALL round-trip
// per probe, NO atomic RMW anywhere. Each wave polls & releases independently.
__device__ __forceinline__ void waitflags(const u32* f, int lane, u32 t0, u32 t1) {
  const u32* p = f + lane;
  const u32 tgt = (lane < 32) ? t0 : t1;
  while (!__all((int)(ldflag(p) >= tgt)))
    __builtin_amdgcn_s_sleep(2);
}

// Persistent fused 2-layer GRU: decoupled producer/consumer pipeline, zero
// steady-state fences, zero steady-state atomics, per-WG flag handshake,
// coalesced publish, y via private slab + final reduction.
__global__ __launch_bounds__(256, 1) void gru_fused(
    const float* __restrict__ xin, const float* __restrict__ h1in, const float* __restrict__ h2in,
    const float* __restrict__ Wih1, const float* __restrict__ Whh1,
    const float* __restrict__ bih1, const float* __restrict__ bhh1,
    const float* __restrict__ Wih2, const float* __restrict__ Whh2,
    const float* __restrict__ bih2, const float* __restrict__ bhh2,
    const float* __restrict__ Wfc, const float* __restrict__ bfc,
    float* __restrict__ out, u16* __restrict__ wsb, unsigned* __restrict__ barc)
{
  const int bid   = blockIdx.x;
  const int rb    = bid & 3;
  const int layer = (bid >> 2) & 1;
  const int cbl   = bid >> 3;
  const int n0    = cbl * 16;
  const int wid   = bid >> 2;
  const int tid   = threadIdx.x;
  const int w     = tid >> 6;
  const int lane  = tid & 63;
  const int quad  = lane >> 4;
  const int m16   = lane & 15;

  u16* x0  = wsb;                     // [512][576] bf16 (immutable after init)
  u16* x1  = x0 + 512 * 576;          // shifted copy
  u16* h1r = x1 + 512 * 576;          // 4-slot ring, layer-0 local
  u16* h2r = h1r + 4 * HS;            // 4-slot ring, layer-1 local
  u16* h1m = h2r + 4 * HS;            // 4-slot MALL mirror of h1
  u32* ysl = (u32*)(h1m + 4 * HS);    // y slab [32 cb][512 row][64 t] fp32

  __shared__ short8 wlds[96 * 64];    // 96 KB weight fragments
  __shared__ u32 stage[4 * 288];      // per-wave transpose stage (9-dw pad)

  u32* flags  = barc + rb * 64;       // [64] per-WG step flags (no RMW)
  u32* myflag = flags + (layer ? 32 : 0) + cbl;
  u32* cinit  = barc + 320;
  u32* cfin   = barc + 324;

  const float* Wih = layer ? Wih2 : Wih1;
  const float* Whh = layer ? Whh2 : Whh1;
  const float* bih = layer ? bih2 : bih1;
  const float* bhh = layer ? bhh2 : bhh1;

  // ---------------- one-time init ----------------
  for (int i = wid * 256 + tid; i < 128 * 575; i += 64 * 256) {
    int r = i / 575, c = i - r * 575;
    int row = rb * 128 + r;
    u16 bv = f2bf(xin[row * 575 + c]);
    x0[row * 576 + c] = bv;
    if (c >= 1) x1[row * 576 + (c - 1)] = bv;
  }
  for (int i = wid * 256 + tid; i < 128 * 512; i += 64 * 256) {
    int r = i >> 9, c = i & 511;
    int row = rb * 128 + r;
    h1r[3 * HS + row * 512 + c] = f2bf(h1in[row * 512 + c]);
    h2r[3 * HS + row * 512 + c] = f2bf(h2in[row * 512 + c]);
  }
  for (int i = tid; i < 96 * 64; i += 256) {
    int blk = i >> 6, l = i & 63;
    int s, gr;
    if (blk < 64) { s = blk & 31; gr = (blk >> 5) * 512; }   // r / z, K=1024
    else          { s = blk - 64; gr = 1024; }               // i_n (s<16) / h_n (s>=16)
    int n  = n0 + (l & 15);
    int k0 = s * 32 + (l >> 4) * 8;
    short8 pk;
    #pragma unroll
    for (int j = 0; j < 8; ++j) {
      int k = k0 + j;
      float v = (k < 512) ? Wih[(gr + n) * 512 + k] : Whh[(gr + n) * 512 + (k - 512)];
      pk[j] = (short)f2bf(v);
    }
    wlds[blk * 64 + l] = pk;
  }

  float hreg[2][4];
  const float* hin = layer ? h2in : h1in;
  #pragma unroll
  for (int rf = 0; rf < 2; ++rf)
    #pragma unroll
    for (int q = 0; q < 4; ++q)
      hreg[rf][q] = hin[(rb * 128 + (2 * w + rf) * 16 + quad * 4 + q) * 512 + n0 + m16];

  const int nn = n0 + m16;
  const float bias_r  = bih[nn] + bhh[nn];
  const float bias_z  = bih[512 + nn] + bhh[512 + nn];
  const float bias_in = bih[1024 + nn];
  const float bias_hn = bhh[1024 + nn];
  const float bfcv = bfc[0];
  float wfc8[8];
  #pragma unroll
  for (int k = 0; k < 8; ++k) wfc8[k] = Wfc[n0 + (lane & 1) * 8 + k];

  // one-time init barrier with release/acquire (flush seeds + drop stale L2)
  __syncthreads();
  if (tid == 0) {
    __builtin_amdgcn_fence(__ATOMIC_RELEASE, "agent");
    __hip_atomic_fetch_add(cinit, 1u, __ATOMIC_RELAXED, __HIP_MEMORY_SCOPE_AGENT);
    while (__hip_atomic_load(cinit, __ATOMIC_RELAXED, __HIP_MEMORY_SCOPE_AGENT) < 256u)
      __builtin_amdgcn_s_sleep(1);
    __builtin_amdgcn_fence(__ATOMIC_ACQUIRE, "agent");
  }
  __syncthreads();

  const int arow0 = rb * 128 + (2 * w) * 16 + m16;
  const int arow1 = arow0 + 16;
  const int rl    = lane >> 1;
  const int hl    = lane & 1;
  const int growt = rb * 128 + w * 32 + rl;

  if (layer == 0) {
    // =================== producer: h1(u) ===================
    for (int u = 0; u < 64; ++u) {
      f32x4 acc[2][4] = {};
      // x-half before the wait (overlaps peers' completion)
      {
        const int c = u & 1;
        const u16* xc = c ? x1 : x0;
        const u32* pa0 = (const u32*)(xc + (size_t)arow0 * 576 + (u - c) + quad * 8);
        const u32* pa1 = (const u32*)(xc + (size_t)arow1 * 576 + (u - c) + quad * 8);
        #pragma unroll
        for (int s = 0; s < 16; ++s) {
          union { short8 v; u32 u4[4]; } a0, a1;
          #pragma unroll
          for (int j = 0; j < 4; ++j) { a0.u4[j] = pa0[s * 16 + j]; a1.u4[j] = pa1[s * 16 + j]; }
          short8 br = wlds[(s)      * 64 + lane];
          short8 bz = wlds[(32 + s) * 64 + lane];
          short8 bi = wlds[(64 + s) * 64 + lane];
          acc[0][0] = MFMA(a0.v, br, acc[0][0], 0, 0, 0);
          acc[1][0] = MFMA(a1.v, br, acc[1][0], 0, 0, 0);
          acc[0][1] = MFMA(a0.v, bz, acc[0][1], 0, 0, 0);
          acc[1][1] = MFMA(a1.v, bz, acc[1][1], 0, 0, 0);
          acc[0][2] = MFMA(a0.v, bi, acc[0][2], 0, 0, 0);
          acc[1][2] = MFMA(a1.v, bi, acc[1][2], 0, 0, 0);
        }
      }
      // wait: peers past h1(u-1); consumers past step u-4 (ring slot free)
      waitflags(flags, lane, (u32)u, u >= 4 ? (u32)(u - 3) : 0u);
      // h-half: both row-fragments in one 32-load batch (single latency)
      {
        short8 a[32];
        const u16* slab = h1r + (size_t)((u + 3) & 3) * HS;
        ldg32_sc0(a, slab + (size_t)arow0 * 512 + quad * 8,
                     slab + (size_t)arow1 * 512 + quad * 8);
        #pragma unroll
        for (int s = 0; s < 16; ++s) {
          short8 br = wlds[(16 + s) * 64 + lane];
          short8 bz = wlds[(48 + s) * 64 + lane];
          short8 bh = wlds[(80 + s) * 64 + lane];
          acc[0][0] = MFMA(a[s], br, acc[0][0], 0, 0, 0);
          acc[1][0] = MFMA(a[16 + s], br, acc[1][0], 0, 0, 0);
          acc[0][1] = MFMA(a[s], bz, acc[0][1], 0, 0, 0);
          acc[1][1] = MFMA(a[16 + s], bz, acc[1][1], 0, 0, 0);
          acc[0][3] = MFMA(a[s], bh, acc[0][3], 0, 0, 0);
          acc[1][3] = MFMA(a[16 + s], bh, acc[1][3], 0, 0, 0);
        }
      }
      // gates -> stage (in-wave transpose to row-major)
      #pragma unroll
      for (int rf = 0; rf < 2; ++rf)
        #pragma unroll
        for (int q = 0; q < 4; ++q) {
          float rg = sigm(acc[rf][0][q] + bias_r);
          float zg = sigm(acc[rf][1][q] + bias_z);
          float ng = tanhf(acc[rf][2][q] + bias_in + rg * (acc[rf][3][q] + bias_hn));
          float hv = (1.0f - zg) * ng + zg * hreg[rf][q];
          hreg[rf][q] = hv;
          u16 b = f2bf(hv);
          u32 pv = (u32)b | ((u32)(u16)__shfl_xor((int)b, 1) << 16);
          if (!(m16 & 1))
            stage[w * 288 + (rf * 16 + quad * 4 + q) * 9 + (m16 >> 1)] = pv;
        }
      // gather 16B row-run and publish (local plain + mirror sc0sc1)
      {
        i32x4 dv;
        dv.x = (int)stage[w * 288 + rl * 9 + hl * 4 + 0];
        dv.y = (int)stage[w * 288 + rl * 9 + hl * 4 + 1];
        dv.z = (int)stage[w * 288 + rl * 9 + hl * 4 + 2];
        dv.w = (int)stage[w * 288 + rl * 9 + hl * 4 + 3];
        size_t off = (size_t)(u & 3) * HS + (size_t)growt * 512 + n0 + hl * 8;
        *(i32x4*)(h1r + off) = dv;
        stg4_sc01(h1m + off, dv);
      }
      asm volatile("s_waitcnt vmcnt(0)" ::: "memory");
      __syncthreads();                       // all 4 waves' stores drained
      if (tid == 0) stflag(myflag, (u32)(u + 1));
    }
  } else {
    // =================== consumer: h2(v) + y(v) ===================
    for (int v = 0; v < 64; ++v) {
      f32x4 acc[2][4] = {};
      // wait: producer past h1(v) [t0=v+1]; own peers past h2(v-1) [t1=v]
      waitflags(flags, lane, (u32)(v + 1), (u32)v);
      // h2-half: local L2 (sc0), 32 loads one batch
      {
        short8 a[32];
        const u16* slab = h2r + (size_t)((v + 3) & 3) * HS;
        ldg32_sc0(a, slab + (size_t)arow0 * 512 + quad * 8,
                     slab + (size_t)arow1 * 512 + quad * 8);
        #pragma unroll
        for (int s = 0; s < 16; ++s) {
          short8 br = wlds[(16 + s) * 64 + lane];
          short8 bz = wlds[(48 + s) * 64 + lane];
          short8 bh = wlds[(80 + s) * 64 + lane];
          acc[0][0] = MFMA(a[s], br, acc[0][0], 0, 0, 0);
          acc[1][0] = MFMA(a[16 + s], br, acc[1][0], 0, 0, 0);
          acc[0][1] = MFMA(a[s], bz, acc[0][1], 0, 0, 0);
          acc[1][1] = MFMA(a[16 + s], bz, acc[1][1], 0, 0, 0);
          acc[0][3] = MFMA(a[s], bh, acc[0][3], 0, 0, 0);
          acc[1][3] = MFMA(a[16 + s], bh, acc[1][3], 0, 0, 0);
        }
      }
      // h1-half: MALL mirror (sc0 sc1), 32 loads one batch
      {
        short8 a[32];
        const u16* slab = h1m + (size_t)(v & 3) * HS;
        ldg32_sc01(a, slab + (size_t)arow0 * 512 + quad * 8,
                      slab + (size_t)arow1 * 512 + quad * 8);
        #pragma unroll
        for (int s = 0; s < 16; ++s) {
          short8 br = wlds[(s)      * 64 + lane];
          short8 bz = wlds[(32 + s) * 64 + lane];
          short8 bi = wlds[(64 + s) * 64 + lane];
          acc[0][0] = MFMA(a[s], br, acc[0][0], 0, 0, 0);
          acc[1][0] = MFMA(a[16 + s], br, acc[1][0], 0, 0, 0);
          acc[0][1] = MFMA(a[s], bz, acc[0][1], 0, 0, 0);
          acc[1][1] = MFMA(a[16 + s], bz, acc[1][1], 0, 0, 0);
          acc[0][2] = MFMA(a[s], bi, acc[0][2], 0, 0, 0);
          acc[1][2] = MFMA(a[16 + s], bi, acc[1][2], 0, 0, 0);
        }
      }
      // gates -> stage
      #pragma unroll
      for (int rf = 0; rf < 2; ++rf)
        #pragma unroll
        for (int q = 0; q < 4; ++q) {
          float rg = sigm(acc[rf][0][q] + bias_r);
          float zg = sigm(acc[rf][1][q] + bias_z);
          float ng = tanhf(acc[rf][2][q] + bias_in + rg * (acc[rf][3][q] + bias_hn));
          float hv = (1.0f - zg) * ng + zg * hreg[rf][q];
          hreg[rf][q] = hv;
          u16 b = f2bf(hv);
          u32 pv = (u32)b | ((u32)(u16)__shfl_xor((int)b, 1) << 16);
          if (!(m16 & 1))
            stage[w * 288 + (rf * 16 + quad * 4 + q) * 9 + (m16 >> 1)] = pv;
        }
      // gather + publish h2 (local) + y partial to slab (sc0sc1)
      {
        i32x4 dv;
        dv.x = (int)stage[w * 288 + rl * 9 + hl * 4 + 0];
        dv.y = (int)stage[w * 288 + rl * 9 + hl * 4 + 1];
        dv.z = (int)stage[w * 288 + rl * 9 + hl * 4 + 2];
        dv.w = (int)stage[w * 288 + rl * 9 + hl * 4 + 3];
        size_t off = (size_t)(v & 3) * HS + (size_t)growt * 512 + n0 + hl * 8;
        *(i32x4*)(h2r + off) = dv;
        float yl = 0.0f;
        u32 dd[4] = {(u32)dv.x, (u32)dv.y, (u32)dv.z, (u32)dv.w};
        #pragma unroll
        for (int j = 0; j < 4; ++j) {
          yl += bf2f(dd[j] << 16) * wfc8[2 * j];
          yl += bf2f(dd[j] & 0xffff0000u) * wfc8[2 * j + 1];
        }
        yl += __shfl_xor(yl, 1);
        if (!hl) {
          union { float f; u32 u; } yu; yu.f = yl;
          stg1_sc01(ysl + ((size_t)(cbl * 512 + growt) * 64 + v), yu.u);
        }
      }
      asm volatile("s_waitcnt vmcnt(0)" ::: "memory");
      __syncthreads();
      if (tid == 0) stflag(myflag, (u32)(v + 1));
    }
  }

  // final hidden states from registers (fp32 exact)
  float* hout = out + 32768 + layer * (512 * 512);
  #pragma unroll
  for (int rf = 0; rf < 2; ++rf)
    #pragma unroll
    for (int q = 0; q < 4; ++q) {
      int row = rb * 128 + (2 * w + rf) * 16 + quad * 4 + q;
      hout[row * 512 + nn] = hreg[rf][q];
    }

  // grid-wide completion, then y reduction (32 partials per output)
  asm volatile("s_waitcnt vmcnt(0)" ::: "memory");
  __syncthreads();
  if (tid == 0)
    __hip_atomic_fetch_add(cfin, 1u, __ATOMIC_RELAXED, __HIP_MEMORY_SCOPE_AGENT);
  while (__hip_atomic_load(cfin, __ATOMIC_RELAXED, __HIP_MEMORY_SCOPE_AGENT) < 256u)
    __builtin_amdgcn_s_sleep(1);

  if (tid < 128) {
    int row = 2 * bid + (tid >> 6);
    int t   = tid & 63;
    float acc = bfcv;
    #pragma unroll
    for (int cb = 0; cb < 32; ++cb) {
      u32 bits = __hip_atomic_load(ysl + ((size_t)(cb * 512 + row) * 64 + t),
                                   __ATOMIC_RELAXED, __HIP_MEMORY_SCOPE_AGENT);
      union { u32 u; float f; } cv; cv.u = bits;
      acc += cv.f;
    }
    out[row * 64 + t] = acc;
  }
}

extern "C" void kernel_launch(void* const* d_in, const int* in_sizes, int n_in,
                              void* d_out, int out_size, void* d_ws, size_t ws_size,
                              hipStream_t stream) {
  (void)in_sizes; (void)n_in; (void)out_size; (void)ws_size;
  (void)hipMemsetAsync(d_ws, 0, 4096, stream);               // flags + counters
  unsigned* bar = (unsigned*)d_ws;
  u16* wsb = (u16*)((char*)d_ws + 4096);
  gru_fused<<<256, 256, 0, stream>>>(
      (const float*)d_in[0], (const float*)d_in[1], (const float*)d_in[2],
      (const float*)d_in[3], (const float*)d_in[4], (const float*)d_in[5], (const float*)d_in[6],
      (const float*)d_in[7], (const float*)d_in[8], (const float*)d_in[9], (const float*)d_in[10],
      (const float*)d_in[11], (const float*)d_in[12],
      (float*)d_out, wsb, bar);
}